// Round 9
// baseline (334.789 us; speedup 1.0000x reference)
//
#include <hip/hip_runtime.h>
#include <stdint.h>

// Problem constants (B=1)
#define L_SEQ 2048
#define DMODEL 1024
#define DI_DIM 2048
#define NSSM 16
#define NPROJ 2080        // DI + 2N
#define NCHUNK 64
#define LCHUNK 32         // NCHUNK*LCHUNK == L_SEQ

typedef __attribute__((ext_vector_type(8))) short bf16x8;
typedef __attribute__((ext_vector_type(4))) float f32x4;

__device__ __forceinline__ float bf2f(unsigned short u) {
  union { uint32_t u; float f; } v; v.u = (uint32_t)u << 16; return v.f;
}
__device__ __forceinline__ unsigned short f2bf(float f) {
  union { float f; uint32_t u; } v; v.f = f;
  uint32_t u = v.u;
  return (unsigned short)((u + 0x7fffu + ((u >> 16) & 1u)) >> 16);
}
__device__ __forceinline__ void async16(const void* g, void* l) {
  __builtin_amdgcn_global_load_lds(
      (__attribute__((address_space(1))) void*)(g),
      (__attribute__((address_space(3))) void*)(l), 16, 0, 0);
}
// native-op math (no libm: default compile is non-fast-math and log1pf/fdiv
// expand to huge sequences -- measured 4x VALU inflation in scan kernels)
__device__ __forceinline__ float softplusf(float p) {
  return (p > 20.f) ? p : __logf(1.f + __expf(p));
}
__device__ __forceinline__ float siluf(float x) {
  return x * __builtin_amdgcn_rcpf(1.f + __expf(-x));
}

// ---------------- fused f32 -> bf16 converts (x, W_in, W_x) ----------------
#define CVT_N1 524288                    // x:    2048*1024/4
#define CVT_N2 (CVT_N1 + 1048576)        // W_in: 4096*1024/4
#define CVT_N3 (CVT_N2 + 1064960)        // W_x:  2080*2048/4
__global__ void k_convert3(const float* __restrict__ x, const float* __restrict__ win,
                           const float* __restrict__ wx, unsigned short* __restrict__ xb,
                           unsigned short* __restrict__ winb, unsigned short* __restrict__ wxb) {
  int i = blockIdx.x * 256 + threadIdx.x;
  const float4* src; unsigned short* dst; int j;
  if (i < CVT_N1)      { src = (const float4*)x;   dst = xb;   j = i; }
  else if (i < CVT_N2) { src = (const float4*)win; dst = winb; j = i - CVT_N1; }
  else if (i < CVT_N3) { src = (const float4*)wx;  dst = wxb;  j = i - CVT_N2; }
  else return;
  float4 v = src[j];
  ushort4 o;
  o.x = f2bf(v.x); o.y = f2bf(v.y); o.z = f2bf(v.z); o.w = f2bf(v.w);
  ((ushort4*)dst)[j] = o;
}

__global__ void k_f32_to_bf16(const float* __restrict__ in,
                              unsigned short* __restrict__ out, int n4) {
  int i = blockIdx.x * blockDim.x + threadIdx.x;
  if (i < n4) {
    const float4 v = ((const float4*)in)[i];
    ushort4 o;
    o.x = f2bf(v.x); o.y = f2bf(v.y); o.z = f2bf(v.z); o.w = f2bf(v.w);
    ((ushort4*)out)[i] = o;
  }
}

// ---------------- bf16 N-T GEMM: C = A[M,K] * B[N,K]^T (+bias) ----------------
// 64x128 tile, BK=32, double-buffered LDS, __syncthreads K-loop (proven r7).
// CONFLICT-FREE LDS GEOMETRY: each 16-row x 32-K block is staged so lane l
// fetches global (row = l&15, k = (l>>4)*8) and lands at LDS byte l*16.
// Since the MFMA A/B fragment is exactly (m=lane&15, k=(lane>>4)*8+j), every
// fragment read is ds_read_b128 at base + lane*16 -> sequential banks, zero
// conflicts (r7 measured SQ_LDS_BANK_CONFLICT=3.34M with the row-major layout).
// gridDim.z>1: split-K, block z writes its partial to C + z*M*N, no bias.
template <typename OutT>
__global__ __launch_bounds__(256) void k_gemm_bt(
    const unsigned short* __restrict__ A, const unsigned short* __restrict__ B,
    const float* __restrict__ bias, OutT* __restrict__ C,
    int M, int N, int K) {
  __shared__ unsigned short As[2][64 * 32];    // 4 blocks x 1 KB per buffer
  __shared__ unsigned short Bs[2][128 * 32];   // 8 blocks x 1 KB per buffer
  const int tid = threadIdx.x;
  const int wave = tid >> 6;
  const int lane = tid & 63;
  const int m0 = blockIdx.y * 64;
  const int n0 = blockIdx.x * 128;
  const int kLen = K / gridDim.z;
  const int kLo = blockIdx.z * kLen;

  // staging source: lane -> (row = base + (lane&15), k = (lane>>4)*8)
  const int lr = lane & 15;
  const int lk = (lane >> 4) * 8;
  int ar = m0 + wave * 16 + lr;           if (ar > M - 1) ar = M - 1;
  int br0 = n0 + wave * 32 + lr;          if (br0 > N - 1) br0 = N - 1;
  int br1 = n0 + wave * 32 + 16 + lr;     if (br1 > N - 1) br1 = N - 1;
  const unsigned short* ap  = A + (size_t)ar * K + lk + kLo;
  const unsigned short* bp0 = B + (size_t)br0 * K + lk + kLo;
  const unsigned short* bp1 = B + (size_t)br1 * K + lk + kLo;
  const int soA  = wave * 512;            // A block w at w*1024 bytes
  const int soB0 = (wave * 2) * 512;      // B blocks 2w, 2w+1
  const int soB1 = (wave * 2 + 1) * 512;
  const int lo8 = lane * 8;               // fragment read: lane*16 bytes

  f32x4 acc[4][2];
#pragma unroll
  for (int i = 0; i < 4; i++)
#pragma unroll
    for (int j = 0; j < 2; j++) acc[i][j] = (f32x4){0.f, 0.f, 0.f, 0.f};

  const int niter = kLen / 32;   // even for all our shapes

  // prologue: stage tile 0 into buffer 0
  async16(ap, &As[0][soA]);
  async16(bp0, &Bs[0][soB0]);
  async16(bp1, &Bs[0][soB1]);

#define GEMM_COMPUTE(BUF)                                                      \
  {                                                                            \
    bf16x8 af[4], bfv[2];                                                      \
    _Pragma("unroll")                                                          \
    for (int i = 0; i < 4; i++)                                                \
      af[i] = *(const bf16x8*)&As[BUF][i * 512 + lo8];                         \
    _Pragma("unroll")                                                          \
    for (int j = 0; j < 2; j++)                                                \
      bfv[j] = *(const bf16x8*)&Bs[BUF][(wave * 2 + j) * 512 + lo8];           \
    _Pragma("unroll")                                                          \
    for (int i = 0; i < 4; i++)                                                \
      _Pragma("unroll")                                                        \
      for (int j = 0; j < 2; j++)                                              \
        acc[i][j] = __builtin_amdgcn_mfma_f32_16x16x32_bf16(af[i], bfv[j],     \
                                                            acc[i][j], 0, 0, 0); \
  }

  for (int it = 0; it < niter; it += 2) {
    __syncthreads();
    {
      int kt = (it + 1) * 32;
      async16(ap + kt, &As[1][soA]);
      async16(bp0 + kt, &Bs[1][soB0]);
      async16(bp1 + kt, &Bs[1][soB1]);
    }
    GEMM_COMPUTE(0)
    __syncthreads();
    if (it + 2 < niter) {
      int kt = (it + 2) * 32;
      async16(ap + kt, &As[0][soA]);
      async16(bp0 + kt, &Bs[0][soB0]);
      async16(bp1 + kt, &Bs[0][soB1]);
    }
    GEMM_COMPUTE(1)
  }
#undef GEMM_COMPUTE

  // epilogue: C/D layout col=lane&15, row=(lane>>4)*4+reg (verified mapping)
  const bool withBias = (gridDim.z == 1);
  OutT* Cz = C + (size_t)blockIdx.z * ((size_t)M * N);
#pragma unroll
  for (int j = 0; j < 2; j++) {
    int col = n0 + wave * 32 + j * 16 + (lane & 15);
    if (col < N) {
      float bv = withBias ? bias[col] : 0.f;
#pragma unroll
      for (int i = 0; i < 4; i++) {
        int rbase = m0 + i * 16 + (lane >> 4) * 4;
#pragma unroll
        for (int r = 0; r < 4; r++) {
          float v = acc[i][j][r] + bv;
          if constexpr (sizeof(OutT) == 2)
            Cz[(size_t)(rbase + r) * N + col] = (OutT)f2bf(v);
          else
            Cz[(size_t)(rbase + r) * N + col] = (OutT)v;
        }
      }
    }
  }
}

// ---------------- split-K reduce: out = p0 + p1 + bias ----------------
__global__ void k_reduce_out(const float* __restrict__ part, const float* __restrict__ bias,
                             float* __restrict__ out) {
  int i = blockIdx.x * 256 + threadIdx.x;   // float4 index over 2048*1024
  float4 a = ((const float4*)part)[i];
  float4 b = ((const float4*)(part + (size_t)L_SEQ * DMODEL))[i];
  int col = (i * 4) & (DMODEL - 1);
  float4 bb = *(const float4*)&bias[col];
  float4 o;
  o.x = a.x + b.x + bb.x; o.y = a.y + b.y + bb.y;
  o.z = a.z + b.z + bb.z; o.w = a.w + b.w + bb.w;
  ((float4*)out)[i] = o;
}

// ---------------- depthwise causal conv (K=4) + bias + SiLU ----------------
__global__ void k_conv_silu(const unsigned short* __restrict__ xr,
                            const float* __restrict__ Wc,
                            const float* __restrict__ bc,
                            unsigned short* __restrict__ xcb) {
  int idx = blockIdx.x * blockDim.x + threadIdx.x;
  if (idx >= L_SEQ * DI_DIM) return;
  int t = idx >> 11;
  int d = idx & (DI_DIM - 1);
  float acc = bc[d];
  const float* wd = Wc + d * 4;
  if (t >= 3) acc += bf2f(xr[(size_t)(t - 3) * (2 * DI_DIM) + d]) * wd[0];
  if (t >= 2) acc += bf2f(xr[(size_t)(t - 2) * (2 * DI_DIM) + d]) * wd[1];
  if (t >= 1) acc += bf2f(xr[(size_t)(t - 1) * (2 * DI_DIM) + d]) * wd[2];
  acc += bf2f(xr[(size_t)t * (2 * DI_DIM) + d]) * wd[3];
  xcb[idx] = f2bf(siluf(acc));
}

// ---------------- scan phase A: per-chunk local scan ----------------
__global__ __launch_bounds__(256) void k_scan_a(
    const float* __restrict__ proj, const unsigned short* __restrict__ xcb,
    const float* __restrict__ A_log,
    float* __restrict__ Sdelta, float* __restrict__ hstate) {
  __shared__ float Bsh[LCHUNK * NSSM];
  const int d = blockIdx.x * 256 + threadIdx.x;
  const int c = blockIdx.y;
  const int t0 = c * LCHUNK;
  for (int i = threadIdx.x; i < LCHUNK * NSSM; i += 256) {
    int t = i >> 4, n = i & 15;
    Bsh[i] = proj[(size_t)(t0 + t) * NPROJ + DI_DIM + n];
  }
  __syncthreads();
  float Ar[NSSM], h[NSSM];
#pragma unroll
  for (int n = 0; n < NSSM; n++) {
    Ar[n] = -__expf(A_log[d * NSSM + n]);
    h[n] = 0.f;
  }
  const float* pp = proj + (size_t)t0 * NPROJ + d;
  const unsigned short* xp = xcb + (size_t)t0 * DI_DIM + d;
  float p_nxt = pp[0];
  unsigned short x_nxt = xp[0];
  float sd = 0.f;
  for (int t = 0; t < LCHUNK; t++) {
    float p = p_nxt;
    unsigned short xu = x_nxt;
    if (t + 1 < LCHUNK) {                          // prefetch next step
      p_nxt = pp[(size_t)(t + 1) * NPROJ];
      x_nxt = xp[(size_t)(t + 1) * DI_DIM];
    }
    float delta = softplusf(p);
    float dx = delta * bf2f(xu);
    sd += delta;
#pragma unroll
    for (int n = 0; n < NSSM; n++)
      h[n] = __expf(delta * Ar[n]) * h[n] + dx * Bsh[t * NSSM + n];
  }
  Sdelta[(size_t)c * DI_DIM + d] = sd;
#pragma unroll
  for (int n = 0; n < NSSM; n++)
    hstate[((size_t)c * DI_DIM + d) * NSSM + n] = h[n];
}

// ---------------- scan phase B: combine across chunks (in-place) ----------------
__global__ void k_scan_b(const float* __restrict__ A_log,
                         const float* __restrict__ Sdelta,
                         float* __restrict__ hstate) {
  int tid = blockIdx.x * 256 + threadIdx.x;  // d*16+n
  int d = tid >> 4;
  float A = -__expf(A_log[tid]);
  float carry = 0.f;
  float v_nxt = hstate[tid];
  float s_nxt = Sdelta[d];
  for (int c = 0; c < NCHUNK; c++) {
    float v = v_nxt, s = s_nxt;
    if (c + 1 < NCHUNK) {                          // prefetch next chunk
      v_nxt = hstate[(size_t)(c + 1) * DI_DIM * NSSM + tid];
      s_nxt = Sdelta[(size_t)(c + 1) * DI_DIM + d];
    }
    hstate[(size_t)c * DI_DIM * NSSM + tid] = carry;
    carry = __expf(A * s) * carry + v;
  }
}

// ---------------- scan phase C: replay with h0, produce y*silu(res) ----------------
__global__ __launch_bounds__(256) void k_scan_c(
    const float* __restrict__ proj, const unsigned short* __restrict__ xcb,
    const float* __restrict__ A_log, const float* __restrict__ h0,
    const float* __restrict__ Dvec, const unsigned short* __restrict__ xr,
    unsigned short* __restrict__ ybf) {
  __shared__ float Bsh[LCHUNK * NSSM];
  __shared__ float Csh[LCHUNK * NSSM];
  const int d = blockIdx.x * 256 + threadIdx.x;
  const int c = blockIdx.y;
  const int t0 = c * LCHUNK;
  for (int i = threadIdx.x; i < LCHUNK * NSSM; i += 256) {
    int t = i >> 4, n = i & 15;
    Bsh[i] = proj[(size_t)(t0 + t) * NPROJ + DI_DIM + n];
    Csh[i] = proj[(size_t)(t0 + t) * NPROJ + DI_DIM + NSSM + n];
  }
  __syncthreads();
  float Ar[NSSM], h[NSSM];
#pragma unroll
  for (int n = 0; n < NSSM; n++) {
    Ar[n] = -__expf(A_log[d * NSSM + n]);
    h[n] = h0[((size_t)c * DI_DIM + d) * NSSM + n];
  }
  float Dd = Dvec[d];
  const float* pp = proj + (size_t)t0 * NPROJ + d;
  const unsigned short* xp = xcb + (size_t)t0 * DI_DIM + d;
  const unsigned short* rp = xr + (size_t)t0 * (2 * DI_DIM) + DI_DIM + d;
  float p_nxt = pp[0];
  unsigned short x_nxt = xp[0];
  unsigned short r_nxt = rp[0];
  for (int t = 0; t < LCHUNK; t++) {
    float p = p_nxt;
    unsigned short xu = x_nxt, ru = r_nxt;
    if (t + 1 < LCHUNK) {                          // prefetch next step
      p_nxt = pp[(size_t)(t + 1) * NPROJ];
      x_nxt = xp[(size_t)(t + 1) * DI_DIM];
      r_nxt = rp[(size_t)(t + 1) * (2 * DI_DIM)];
    }
    float delta = softplusf(p);
    float xi = bf2f(xu);
    float dx = delta * xi;
    float y = 0.f;
#pragma unroll
    for (int n = 0; n < NSSM; n++) {
      h[n] = __expf(delta * Ar[n]) * h[n] + dx * Bsh[t * NSSM + n];
      y += h[n] * Csh[t * NSSM + n];
    }
    y += xi * Dd;
    y *= siluf(bf2f(ru));
    ybf[(size_t)(t0 + t) * DI_DIM + d] = f2bf(y);
  }
}

extern "C" void kernel_launch(void* const* d_in, const int* in_sizes, int n_in,
                              void* d_out, int out_size, void* d_ws, size_t ws_size,
                              hipStream_t stream) {
  const float* x      = (const float*)d_in[0];
  const float* W_in   = (const float*)d_in[1];
  const float* b_in   = (const float*)d_in[2];
  const float* W_conv = (const float*)d_in[3];
  const float* b_conv = (const float*)d_in[4];
  const float* W_x    = (const float*)d_in[5];
  const float* b_x    = (const float*)d_in[6];
  const float* W_out  = (const float*)d_in[7];
  const float* b_out  = (const float*)d_in[8];
  const float* A_log  = (const float*)d_in[9];
  const float* Dv     = (const float*)d_in[10];
  float* out = (float*)d_out;

  char* ws = (char*)d_ws;
  size_t off = 0;
  auto alloc = [&](size_t bytes) { void* p = ws + off; off += (bytes + 255) & ~(size_t)255; return p; };
  unsigned short* win_bf = (unsigned short*)alloc((size_t)4096 * DMODEL * 2);        // 8.39 MB; reused as ybf
  unsigned short* wx_bf  = (unsigned short*)alloc((size_t)NPROJ * DI_DIM * 2);       // 8.52 MB
  unsigned short* x_bf   = (unsigned short*)alloc((size_t)L_SEQ * DMODEL * 2);       // 4.19 MB; reused as wout_bf
  unsigned short* xr_bf  = (unsigned short*)alloc((size_t)L_SEQ * 2 * DI_DIM * 2);   // 16.78 MB
  unsigned short* xcb    = (unsigned short*)alloc((size_t)L_SEQ * DI_DIM * 2);       // 8.39 MB
  float* proj            = (float*)alloc((size_t)L_SEQ * NPROJ * 4);                 // 17.04 MB; reused as GEMM3 partials
  float* Sdelta          = (float*)alloc((size_t)NCHUNK * DI_DIM * 4);               // 0.52 MB
  float* hstate          = (float*)alloc((size_t)NCHUNK * DI_DIM * NSSM * 4);        // 8.39 MB
  if (off > ws_size) return;  // proven budget: 72.2 MB
  unsigned short* ybf     = win_bf;  // dead after GEMM1, reborn as y (scan_c -> GEMM3)
  unsigned short* wout_bf = x_bf;    // dead after GEMM1, reborn as W_out bf16
  float* part             = proj;    // dead after scan_c, reborn as GEMM3 split-K partials (2 x 8.39 MB)

  // fused converts: x, W_in, W_x
  k_convert3<<<CVT_N3 / 256, 256, 0, stream>>>(x, W_in, W_x, x_bf, win_bf, wx_bf);

  // GEMM1: xr = x @ W_in^T + b_in (2048x4096, K=1024), bf16 out, 1024 blocks
  {
    dim3 g(4096 / 128, L_SEQ / 64);
    k_gemm_bt<unsigned short><<<g, 256, 0, stream>>>(x_bf, win_bf, b_in, xr_bf, L_SEQ, 4096, DMODEL);
  }
  // convert W_out into x_bf's slot (x dead after GEMM1)
  k_f32_to_bf16<<<(DMODEL * DI_DIM / 4) / 256, 256, 0, stream>>>(W_out, wout_bf, DMODEL * DI_DIM / 4);
  // depthwise conv + SiLU
  k_conv_silu<<<(L_SEQ * DI_DIM) / 256, 256, 0, stream>>>(xr_bf, W_conv, b_conv, xcb);
  // GEMM2: proj = xi @ W_x^T + b_x (2048x2080, K=2048), f32 out, 544 blocks
  {
    dim3 g((NPROJ + 127) / 128, L_SEQ / 64);
    k_gemm_bt<float><<<g, 256, 0, stream>>>(xcb, wx_bf, b_x, proj, L_SEQ, NPROJ, DI_DIM);
  }
  // selective scan (chunked 3-phase)
  {
    dim3 ga(DI_DIM / 256, NCHUNK);
    k_scan_a<<<ga, 256, 0, stream>>>(proj, xcb, A_log, Sdelta, hstate);
    k_scan_b<<<(DI_DIM * NSSM) / 256, 256, 0, stream>>>(A_log, Sdelta, hstate);
    k_scan_c<<<ga, 256, 0, stream>>>(proj, xcb, A_log, hstate, Dv, xr_bf, ybf);
  }
  // GEMM3: split-K=2 partials (2048x1024, K=1024 each), 512 blocks, then reduce+bias
  {
    dim3 g(DMODEL / 128, L_SEQ / 64, 2);
    k_gemm_bt<float><<<g, 256, 0, stream>>>(ybf, wout_bf, b_out, part, L_SEQ, DMODEL, DI_DIM);
    k_reduce_out<<<(L_SEQ * DMODEL / 4) / 256, 256, 0, stream>>>(part, b_out, out);
  }
}

// Round 10
// 293.582 us; speedup vs baseline: 1.1404x; 1.1404x over previous
//
#include <hip/hip_runtime.h>
#include <stdint.h>

// Problem constants (B=1)
#define L_SEQ 2048
#define DMODEL 1024
#define DI_DIM 2048
#define NSSM 16
#define NPROJ 2080        // DI + 2N
#define NCHUNK 64
#define LCHUNK 32         // NCHUNK*LCHUNK == L_SEQ

typedef __attribute__((ext_vector_type(8))) short bf16x8;
typedef __attribute__((ext_vector_type(4))) float f32x4;

__device__ __forceinline__ float bf2f(unsigned short u) {
  union { uint32_t u; float f; } v; v.u = (uint32_t)u << 16; return v.f;
}
__device__ __forceinline__ unsigned short f2bf(float f) {
  union { float f; uint32_t u; } v; v.f = f;
  uint32_t u = v.u;
  return (unsigned short)((u + 0x7fffu + ((u >> 16) & 1u)) >> 16);
}
__device__ __forceinline__ void async16(const void* g, void* l) {
  __builtin_amdgcn_global_load_lds(
      (__attribute__((address_space(1))) void*)(g),
      (__attribute__((address_space(3))) void*)(l), 16, 0, 0);
}
// native-op math (no libm: default compile is non-fast-math and log1pf/fdiv
// expand to huge sequences -- measured 4x VALU inflation in scan kernels)
__device__ __forceinline__ float softplusf(float p) {
  return (p > 20.f) ? p : __logf(1.f + __expf(p));
}
__device__ __forceinline__ float siluf(float x) {
  return x * __builtin_amdgcn_rcpf(1.f + __expf(-x));
}

// ---------------- fused f32 -> bf16 converts (x, W_in, W_x) ----------------
#define CVT_N1 524288                    // x:    2048*1024/4
#define CVT_N2 (CVT_N1 + 1048576)        // W_in: 4096*1024/4
#define CVT_N3 (CVT_N2 + 1064960)        // W_x:  2080*2048/4
__global__ void k_convert3(const float* __restrict__ x, const float* __restrict__ win,
                           const float* __restrict__ wx, unsigned short* __restrict__ xb,
                           unsigned short* __restrict__ winb, unsigned short* __restrict__ wxb) {
  int i = blockIdx.x * 256 + threadIdx.x;
  const float4* src; unsigned short* dst; int j;
  if (i < CVT_N1)      { src = (const float4*)x;   dst = xb;   j = i; }
  else if (i < CVT_N2) { src = (const float4*)win; dst = winb; j = i - CVT_N1; }
  else if (i < CVT_N3) { src = (const float4*)wx;  dst = wxb;  j = i - CVT_N2; }
  else return;
  float4 v = src[j];
  ushort4 o;
  o.x = f2bf(v.x); o.y = f2bf(v.y); o.z = f2bf(v.z); o.w = f2bf(v.w);
  ((ushort4*)dst)[j] = o;
}

__global__ void k_f32_to_bf16(const float* __restrict__ in,
                              unsigned short* __restrict__ out, int n4) {
  int i = blockIdx.x * blockDim.x + threadIdx.x;
  if (i < n4) {
    const float4 v = ((const float4*)in)[i];
    ushort4 o;
    o.x = f2bf(v.x); o.y = f2bf(v.y); o.z = f2bf(v.z); o.w = f2bf(v.w);
    ((ushort4*)out)[i] = o;
  }
}

// ---------------- bf16 N-T GEMM: C = A[M,K] * B[N,K]^T (+bias) ----------------
// TM x 128 tile (TM = 32 or 64), BK=32, double-buffered LDS, __syncthreads
// K-loop (r7-proven structure).
// XOR-SWIZZLED LDS: staging keeps r7's coalesced global pattern (each quad of
// lanes covers one contiguous 64B row segment) but permutes WHICH 16B chunk a
// lane fetches: lane l -> (row=l>>2, kgroup=(l&3)^((l>>3)&3)). Fragment (m,q)
// then sits at 16B-position 4m + (q^((m>>1)&3)); per quarter-wave the bank
// groups cycle 0,4,1,5,2,6,3,7 twice = conflict-free (r9 measured the row-major
// pattern at 3.34M conflicts; r9's conflict-free variant broke coalescing).
// gridDim.z>1: split-K, block z writes its partial to C + z*M*N, no bias.
template <typename OutT, int TM>
__global__ __launch_bounds__(256) void k_gemm_bt(
    const unsigned short* __restrict__ A, const unsigned short* __restrict__ B,
    const float* __restrict__ bias, OutT* __restrict__ C,
    int M, int N, int K) {
  constexpr int NA = TM / 16;                  // A-blocks (and af count)
  __shared__ unsigned short As[2][TM * 32];
  __shared__ unsigned short Bs[2][128 * 32];
  const int tid = threadIdx.x;
  const int wave = tid >> 6;
  const int lane = tid & 63;
  const int m0 = blockIdx.y * TM;
  const int n0 = blockIdx.x * 128;
  const int kLen = K / gridDim.z;
  const int kLo = blockIdx.z * kLen;

  // staging source: lane l -> row l>>2, kgroup (l&3)^((l>>3)&3)  (swizzled)
  const int srow = lane >> 2;
  const int scol = ((lane & 3) ^ ((lane >> 3) & 3)) * 8;
  int ar = m0 + wave * 16 + srow;         if (ar > M - 1) ar = M - 1;  // used iff wave<NA
  int br0 = n0 + wave * 32 + srow;        if (br0 > N - 1) br0 = N - 1;
  int br1 = n0 + wave * 32 + 16 + srow;   if (br1 > N - 1) br1 = N - 1;
  const unsigned short* ap  = A + (size_t)ar * K + scol + kLo;
  const unsigned short* bp0 = B + (size_t)br0 * K + scol + kLo;
  const unsigned short* bp1 = B + (size_t)br1 * K + scol + kLo;
  const int soA  = wave * 512;            // A block w at w*1024 bytes
  const int soB0 = (wave * 2) * 512;      // B blocks 2w, 2w+1
  const int soB1 = (wave * 2 + 1) * 512;

  // compute-side fragment read: block_base + mrow*32 + swz8 (ushorts)
  const int mrow = lane & 15;
  const int swz8 = (((lane >> 4) ^ ((mrow >> 1) & 3)) * 8);
  const int ro = mrow * 32 + swz8;

  f32x4 acc[NA][2];
#pragma unroll
  for (int i = 0; i < NA; i++)
#pragma unroll
    for (int j = 0; j < 2; j++) acc[i][j] = (f32x4){0.f, 0.f, 0.f, 0.f};

  const int niter = kLen / 32;   // even for all our shapes

#define STAGE(BUF, KT)                                                         \
  {                                                                            \
    if (wave < NA) async16(ap + (KT), &As[BUF][soA]);                          \
    async16(bp0 + (KT), &Bs[BUF][soB0]);                                       \
    async16(bp1 + (KT), &Bs[BUF][soB1]);                                       \
  }

#define GEMM_COMPUTE(BUF)                                                      \
  {                                                                            \
    bf16x8 af[NA], bfv[2];                                                     \
    _Pragma("unroll")                                                          \
    for (int i = 0; i < NA; i++)                                               \
      af[i] = *(const bf16x8*)&As[BUF][i * 512 + ro];                          \
    _Pragma("unroll")                                                          \
    for (int j = 0; j < 2; j++)                                                \
      bfv[j] = *(const bf16x8*)&Bs[BUF][(wave * 2 + j) * 512 + ro];            \
    _Pragma("unroll")                                                          \
    for (int i = 0; i < NA; i++)                                               \
      _Pragma("unroll")                                                        \
      for (int j = 0; j < 2; j++)                                              \
        acc[i][j] = __builtin_amdgcn_mfma_f32_16x16x32_bf16(af[i], bfv[j],     \
                                                            acc[i][j], 0, 0, 0); \
  }

  // prologue: stage tile 0 into buffer 0
  STAGE(0, 0)

  for (int it = 0; it < niter; it += 2) {
    __syncthreads();
    STAGE(1, (it + 1) * 32)
    GEMM_COMPUTE(0)
    __syncthreads();
    if (it + 2 < niter) STAGE(0, (it + 2) * 32)
    GEMM_COMPUTE(1)
  }
#undef STAGE
#undef GEMM_COMPUTE

  // epilogue: C/D layout col=lane&15, row=(lane>>4)*4+reg (verified mapping)
  const bool withBias = (gridDim.z == 1);
  OutT* Cz = C + (size_t)blockIdx.z * ((size_t)M * N);
#pragma unroll
  for (int j = 0; j < 2; j++) {
    int col = n0 + wave * 32 + j * 16 + (lane & 15);
    if (col < N) {
      float bv = withBias ? bias[col] : 0.f;
#pragma unroll
      for (int i = 0; i < NA; i++) {
        int rbase = m0 + i * 16 + (lane >> 4) * 4;
#pragma unroll
        for (int r = 0; r < 4; r++) {
          float v = acc[i][j][r] + bv;
          if constexpr (sizeof(OutT) == 2)
            Cz[(size_t)(rbase + r) * N + col] = (OutT)f2bf(v);
          else
            Cz[(size_t)(rbase + r) * N + col] = (OutT)v;
        }
      }
    }
  }
}

// ---------------- split-K reduce: out = p0 + p1 + bias ----------------
__global__ void k_reduce_out(const float* __restrict__ part, const float* __restrict__ bias,
                             float* __restrict__ out) {
  int i = blockIdx.x * 256 + threadIdx.x;   // float4 index over 2048*1024
  float4 a = ((const float4*)part)[i];
  float4 b = ((const float4*)(part + (size_t)L_SEQ * DMODEL))[i];
  int col = (i * 4) & (DMODEL - 1);
  float4 bb = *(const float4*)&bias[col];
  float4 o;
  o.x = a.x + b.x + bb.x; o.y = a.y + b.y + bb.y;
  o.z = a.z + b.z + bb.z; o.w = a.w + b.w + bb.w;
  ((float4*)out)[i] = o;
}

// ---------------- depthwise causal conv (K=4) + bias + SiLU ----------------
__global__ void k_conv_silu(const unsigned short* __restrict__ xr,
                            const float* __restrict__ Wc,
                            const float* __restrict__ bc,
                            unsigned short* __restrict__ xcb) {
  int idx = blockIdx.x * blockDim.x + threadIdx.x;
  if (idx >= L_SEQ * DI_DIM) return;
  int t = idx >> 11;
  int d = idx & (DI_DIM - 1);
  float acc = bc[d];
  const float* wd = Wc + d * 4;
  if (t >= 3) acc += bf2f(xr[(size_t)(t - 3) * (2 * DI_DIM) + d]) * wd[0];
  if (t >= 2) acc += bf2f(xr[(size_t)(t - 2) * (2 * DI_DIM) + d]) * wd[1];
  if (t >= 1) acc += bf2f(xr[(size_t)(t - 1) * (2 * DI_DIM) + d]) * wd[2];
  acc += bf2f(xr[(size_t)t * (2 * DI_DIM) + d]) * wd[3];
  xcb[idx] = f2bf(siluf(acc));
}

// ---------------- scan phase A: per-chunk local scan ----------------
__global__ __launch_bounds__(256) void k_scan_a(
    const float* __restrict__ proj, const unsigned short* __restrict__ xcb,
    const float* __restrict__ A_log,
    float* __restrict__ Sdelta, float* __restrict__ hstate) {
  __shared__ float Bsh[LCHUNK * NSSM];
  const int d = blockIdx.x * 256 + threadIdx.x;
  const int c = blockIdx.y;
  const int t0 = c * LCHUNK;
  for (int i = threadIdx.x; i < LCHUNK * NSSM; i += 256) {
    int t = i >> 4, n = i & 15;
    Bsh[i] = proj[(size_t)(t0 + t) * NPROJ + DI_DIM + n];
  }
  __syncthreads();
  float Ar[NSSM], h[NSSM];
#pragma unroll
  for (int n = 0; n < NSSM; n++) {
    Ar[n] = -__expf(A_log[d * NSSM + n]);
    h[n] = 0.f;
  }
  const float* pp = proj + (size_t)t0 * NPROJ + d;
  const unsigned short* xp = xcb + (size_t)t0 * DI_DIM + d;
  float p_nxt = pp[0];
  unsigned short x_nxt = xp[0];
  float sd = 0.f;
  for (int t = 0; t < LCHUNK; t++) {
    float p = p_nxt;
    unsigned short xu = x_nxt;
    if (t + 1 < LCHUNK) {                          // prefetch next step
      p_nxt = pp[(size_t)(t + 1) * NPROJ];
      x_nxt = xp[(size_t)(t + 1) * DI_DIM];
    }
    float delta = softplusf(p);
    float dx = delta * bf2f(xu);
    sd += delta;
#pragma unroll
    for (int n = 0; n < NSSM; n++)
      h[n] = __expf(delta * Ar[n]) * h[n] + dx * Bsh[t * NSSM + n];
  }
  Sdelta[(size_t)c * DI_DIM + d] = sd;
#pragma unroll
  for (int n = 0; n < NSSM; n++)
    hstate[((size_t)c * DI_DIM + d) * NSSM + n] = h[n];
}

// ---------------- scan phase B: combine across chunks (in-place) ----------------
__global__ void k_scan_b(const float* __restrict__ A_log,
                         const float* __restrict__ Sdelta,
                         float* __restrict__ hstate) {
  int tid = blockIdx.x * 256 + threadIdx.x;  // d*16+n
  int d = tid >> 4;
  float A = -__expf(A_log[tid]);
  float carry = 0.f;
  float v_nxt = hstate[tid];
  float s_nxt = Sdelta[d];
  for (int c = 0; c < NCHUNK; c++) {
    float v = v_nxt, s = s_nxt;
    if (c + 1 < NCHUNK) {                          // prefetch next chunk
      v_nxt = hstate[(size_t)(c + 1) * DI_DIM * NSSM + tid];
      s_nxt = Sdelta[(size_t)(c + 1) * DI_DIM + d];
    }
    hstate[(size_t)c * DI_DIM * NSSM + tid] = carry;
    carry = __expf(A * s) * carry + v;
  }
}

// ---------------- scan phase C: replay with h0, produce y*silu(res) ----------------
__global__ __launch_bounds__(256) void k_scan_c(
    const float* __restrict__ proj, const unsigned short* __restrict__ xcb,
    const float* __restrict__ A_log, const float* __restrict__ h0,
    const float* __restrict__ Dvec, const unsigned short* __restrict__ xr,
    unsigned short* __restrict__ ybf) {
  __shared__ float Bsh[LCHUNK * NSSM];
  __shared__ float Csh[LCHUNK * NSSM];
  const int d = blockIdx.x * 256 + threadIdx.x;
  const int c = blockIdx.y;
  const int t0 = c * LCHUNK;
  for (int i = threadIdx.x; i < LCHUNK * NSSM; i += 256) {
    int t = i >> 4, n = i & 15;
    Bsh[i] = proj[(size_t)(t0 + t) * NPROJ + DI_DIM + n];
    Csh[i] = proj[(size_t)(t0 + t) * NPROJ + DI_DIM + NSSM + n];
  }
  __syncthreads();
  float Ar[NSSM], h[NSSM];
#pragma unroll
  for (int n = 0; n < NSSM; n++) {
    Ar[n] = -__expf(A_log[d * NSSM + n]);
    h[n] = h0[((size_t)c * DI_DIM + d) * NSSM + n];
  }
  float Dd = Dvec[d];
  const float* pp = proj + (size_t)t0 * NPROJ + d;
  const unsigned short* xp = xcb + (size_t)t0 * DI_DIM + d;
  const unsigned short* rp = xr + (size_t)t0 * (2 * DI_DIM) + DI_DIM + d;
  float p_nxt = pp[0];
  unsigned short x_nxt = xp[0];
  unsigned short r_nxt = rp[0];
  for (int t = 0; t < LCHUNK; t++) {
    float p = p_nxt;
    unsigned short xu = x_nxt, ru = r_nxt;
    if (t + 1 < LCHUNK) {                          // prefetch next step
      p_nxt = pp[(size_t)(t + 1) * NPROJ];
      x_nxt = xp[(size_t)(t + 1) * DI_DIM];
      r_nxt = rp[(size_t)(t + 1) * (2 * DI_DIM)];
    }
    float delta = softplusf(p);
    float xi = bf2f(xu);
    float dx = delta * xi;
    float y = 0.f;
#pragma unroll
    for (int n = 0; n < NSSM; n++) {
      h[n] = __expf(delta * Ar[n]) * h[n] + dx * Bsh[t * NSSM + n];
      y += h[n] * Csh[t * NSSM + n];
    }
    y += xi * Dd;
    y *= siluf(bf2f(ru));
    ybf[(size_t)(t0 + t) * DI_DIM + d] = f2bf(y);
  }
}

extern "C" void kernel_launch(void* const* d_in, const int* in_sizes, int n_in,
                              void* d_out, int out_size, void* d_ws, size_t ws_size,
                              hipStream_t stream) {
  const float* x      = (const float*)d_in[0];
  const float* W_in   = (const float*)d_in[1];
  const float* b_in   = (const float*)d_in[2];
  const float* W_conv = (const float*)d_in[3];
  const float* b_conv = (const float*)d_in[4];
  const float* W_x    = (const float*)d_in[5];
  const float* b_x    = (const float*)d_in[6];
  const float* W_out  = (const float*)d_in[7];
  const float* b_out  = (const float*)d_in[8];
  const float* A_log  = (const float*)d_in[9];
  const float* Dv     = (const float*)d_in[10];
  float* out = (float*)d_out;

  char* ws = (char*)d_ws;
  size_t off = 0;
  auto alloc = [&](size_t bytes) { void* p = ws + off; off += (bytes + 255) & ~(size_t)255; return p; };
  unsigned short* win_bf = (unsigned short*)alloc((size_t)4096 * DMODEL * 2);        // 8.39 MB; reused as ybf
  unsigned short* wx_bf  = (unsigned short*)alloc((size_t)NPROJ * DI_DIM * 2);       // 8.52 MB
  unsigned short* x_bf   = (unsigned short*)alloc((size_t)L_SEQ * DMODEL * 2);       // 4.19 MB; reused as wout_bf
  unsigned short* xr_bf  = (unsigned short*)alloc((size_t)L_SEQ * 2 * DI_DIM * 2);   // 16.78 MB
  unsigned short* xcb    = (unsigned short*)alloc((size_t)L_SEQ * DI_DIM * 2);       // 8.39 MB
  float* proj            = (float*)alloc((size_t)L_SEQ * NPROJ * 4);                 // 17.04 MB; reused as GEMM3 partials
  float* Sdelta          = (float*)alloc((size_t)NCHUNK * DI_DIM * 4);               // 0.52 MB
  float* hstate          = (float*)alloc((size_t)NCHUNK * DI_DIM * NSSM * 4);        // 8.39 MB
  if (off > ws_size) return;  // proven budget: 72.2 MB
  unsigned short* ybf     = win_bf;  // dead after GEMM1, reborn as y (scan_c -> GEMM3)
  unsigned short* wout_bf = x_bf;    // dead after GEMM1, reborn as W_out bf16
  float* part             = proj;    // dead after scan_c, reborn as GEMM3 split-K partials (2 x 8.39 MB)

  // fused converts: x, W_in, W_x
  k_convert3<<<CVT_N3 / 256, 256, 0, stream>>>(x, W_in, W_x, x_bf, win_bf, wx_bf);

  // GEMM1: xr = x @ W_in^T + b_in (2048x4096, K=1024), bf16 out, TM=64, 1024 blocks
  {
    dim3 g(4096 / 128, L_SEQ / 64);
    k_gemm_bt<unsigned short, 64><<<g, 256, 0, stream>>>(x_bf, win_bf, b_in, xr_bf, L_SEQ, 4096, DMODEL);
  }
  // convert W_out into x_bf's slot (x dead after GEMM1)
  k_f32_to_bf16<<<(DMODEL * DI_DIM / 4) / 256, 256, 0, stream>>>(W_out, wout_bf, DMODEL * DI_DIM / 4);
  // depthwise conv + SiLU
  k_conv_silu<<<(L_SEQ * DI_DIM) / 256, 256, 0, stream>>>(xr_bf, W_conv, b_conv, xcb);
  // GEMM2: proj = xi @ W_x^T + b_x (2048x2080, K=2048), f32 out, TM=32, 1088 blocks
  {
    dim3 g((NPROJ + 127) / 128, L_SEQ / 32);
    k_gemm_bt<float, 32><<<g, 256, 0, stream>>>(xcb, wx_bf, b_x, proj, L_SEQ, NPROJ, DI_DIM);
  }
  // selective scan (chunked 3-phase)
  {
    dim3 ga(DI_DIM / 256, NCHUNK);
    k_scan_a<<<ga, 256, 0, stream>>>(proj, xcb, A_log, Sdelta, hstate);
    k_scan_b<<<(DI_DIM * NSSM) / 256, 256, 0, stream>>>(A_log, Sdelta, hstate);
    k_scan_c<<<ga, 256, 0, stream>>>(proj, xcb, A_log, hstate, Dv, xr_bf, ybf);
  }
  // GEMM3: TM=32, split-K=2 partials (1024 blocks), then reduce+bias
  {
    dim3 g(DMODEL / 128, L_SEQ / 32, 2);
    k_gemm_bt<float, 32><<<g, 256, 0, stream>>>(ybf, wout_bf, b_out, part, L_SEQ, DMODEL, DI_DIM);
    k_reduce_out<<<(L_SEQ * DMODEL / 4) / 256, 256, 0, stream>>>(part, b_out, out);
  }
}

// Round 11
// 279.158 us; speedup vs baseline: 1.1993x; 1.0517x over previous
//
#include <hip/hip_runtime.h>
#include <stdint.h>

// Problem constants (B=1)
#define L_SEQ 2048
#define DMODEL 1024
#define DI_DIM 2048
#define NSSM 16
#define NPROJ 2080        // DI + 2N
#define NCHUNK 64
#define LCHUNK 32         // NCHUNK*LCHUNK == L_SEQ

typedef __attribute__((ext_vector_type(8))) short bf16x8;
typedef __attribute__((ext_vector_type(4))) float f32x4;

__device__ __forceinline__ float bf2f(unsigned short u) {
  union { uint32_t u; float f; } v; v.u = (uint32_t)u << 16; return v.f;
}
__device__ __forceinline__ unsigned short f2bf(float f) {
  union { float f; uint32_t u; } v; v.f = f;
  uint32_t u = v.u;
  return (unsigned short)((u + 0x7fffu + ((u >> 16) & 1u)) >> 16);
}
__device__ __forceinline__ void async16(const void* g, void* l) {
  __builtin_amdgcn_global_load_lds(
      (__attribute__((address_space(1))) void*)(g),
      (__attribute__((address_space(3))) void*)(l), 16, 0, 0);
}
// native-op math (libm log1pf/fdiv expand to huge sequences w/o fast-math;
// switching to __logf/__expf/rcp collapsed scan kernels ~3x -- r7 measured)
__device__ __forceinline__ float softplusf(float p) {
  return (p > 20.f) ? p : __logf(1.f + __expf(p));
}
__device__ __forceinline__ float siluf(float x) {
  return x * __builtin_amdgcn_rcpf(1.f + __expf(-x));
}

// ---------------- fused f32 -> bf16 converts (x, W_in, W_x) ----------------
#define CVT_N1 524288                    // x:    2048*1024/4
#define CVT_N2 (CVT_N1 + 1048576)        // W_in: 4096*1024/4
#define CVT_N3 (CVT_N2 + 1064960)        // W_x:  2080*2048/4
__global__ void k_convert3(const float* __restrict__ x, const float* __restrict__ win,
                           const float* __restrict__ wx, unsigned short* __restrict__ xb,
                           unsigned short* __restrict__ winb, unsigned short* __restrict__ wxb) {
  int i = blockIdx.x * 256 + threadIdx.x;
  const float4* src; unsigned short* dst; int j;
  if (i < CVT_N1)      { src = (const float4*)x;   dst = xb;   j = i; }
  else if (i < CVT_N2) { src = (const float4*)win; dst = winb; j = i - CVT_N1; }
  else if (i < CVT_N3) { src = (const float4*)wx;  dst = wxb;  j = i - CVT_N2; }
  else return;
  float4 v = src[j];
  ushort4 o;
  o.x = f2bf(v.x); o.y = f2bf(v.y); o.z = f2bf(v.z); o.w = f2bf(v.w);
  ((ushort4*)dst)[j] = o;
}

__global__ void k_f32_to_bf16(const float* __restrict__ in,
                              unsigned short* __restrict__ out, int n4) {
  int i = blockIdx.x * blockDim.x + threadIdx.x;
  if (i < n4) {
    const float4 v = ((const float4*)in)[i];
    ushort4 o;
    o.x = f2bf(v.x); o.y = f2bf(v.y); o.z = f2bf(v.z); o.w = f2bf(v.w);
    ((ushort4*)out)[i] = o;
  }
}

// ---------------- bf16 N-T GEMM: C = A[M,K] * B[N,K]^T (+bias) ----------------
// TM=64 x 128 tile, KB (32 or 64) K-step, double-buffered LDS, __syncthreads
// K-loop. Factor status from r5-r10 A/B:
//   atomics -40% | LDS>48KB (occupancy) -30% | uncoalesced staging -60%
//   | TM=32 (compute dilution) -25% | row-major LDS conflicts -11%
// This version: all good factors combined. XOR-SWIZZLE (HW-verified r10):
// staging lane l -> (row=l>>2, kgroup=(l&3)^((l>>3)&3)): quad covers one 64B
// row segment (coalesced) while fragment reads land conflict-free.
// KB=64 halves barrier-drain count (use where LDS 48KB >= dispatch blocks/CU).
// gridDim.z>1: split-K, block z writes partial to C + z*M*N, no bias.
template <typename OutT, int KB>
__global__ __launch_bounds__(256) void k_gemm_bt(
    const unsigned short* __restrict__ A, const unsigned short* __restrict__ B,
    const float* __restrict__ bias, OutT* __restrict__ C,
    int M, int N, int K) {
  constexpr int NH = KB / 32;                  // 32-K halves per buffer
  __shared__ unsigned short As[2][NH][64 * 32];
  __shared__ unsigned short Bs[2][NH][128 * 32];
  const int tid = threadIdx.x;
  const int wave = tid >> 6;
  const int lane = tid & 63;
  const int m0 = blockIdx.y * 64;
  const int n0 = blockIdx.x * 128;
  const int kLen = K / gridDim.z;
  const int kLo = blockIdx.z * kLen;

  // staging source: lane l -> row l>>2, kgroup (l&3)^((l>>3)&3)  (swizzled)
  const int srow = lane >> 2;
  const int scol = ((lane & 3) ^ ((lane >> 3) & 3)) * 8;
  int ar = m0 + wave * 16 + srow;         if (ar > M - 1) ar = M - 1;
  int br0 = n0 + wave * 32 + srow;        if (br0 > N - 1) br0 = N - 1;
  int br1 = n0 + wave * 32 + 16 + srow;   if (br1 > N - 1) br1 = N - 1;
  const unsigned short* ap  = A + (size_t)ar * K + scol + kLo;
  const unsigned short* bp0 = B + (size_t)br0 * K + scol + kLo;
  const unsigned short* bp1 = B + (size_t)br1 * K + scol + kLo;
  const int soA  = wave * 512;
  const int soB0 = (wave * 2) * 512;
  const int soB1 = (wave * 2 + 1) * 512;

  // compute-side fragment read: block_base + mrow*32 + swz8 (ushorts)
  const int mrow = lane & 15;
  const int swz8 = (((lane >> 4) ^ ((mrow >> 1) & 3)) * 8);
  const int ro = mrow * 32 + swz8;

  f32x4 acc[4][2];
#pragma unroll
  for (int i = 0; i < 4; i++)
#pragma unroll
    for (int j = 0; j < 2; j++) acc[i][j] = (f32x4){0.f, 0.f, 0.f, 0.f};

  const int niter = kLen / KB;   // even for all our shapes

#define STAGE(BUF, KT)                                                         \
  {                                                                            \
    _Pragma("unroll")                                                          \
    for (int hh = 0; hh < NH; hh++) {                                          \
      async16(ap + (KT) + hh * 32, &As[BUF][hh][soA]);                         \
      async16(bp0 + (KT) + hh * 32, &Bs[BUF][hh][soB0]);                       \
      async16(bp1 + (KT) + hh * 32, &Bs[BUF][hh][soB1]);                       \
    }                                                                          \
  }

#define GEMM_COMPUTE(BUF)                                                      \
  {                                                                            \
    _Pragma("unroll")                                                          \
    for (int hh = 0; hh < NH; hh++) {                                          \
      bf16x8 af[4], bfv[2];                                                    \
      _Pragma("unroll")                                                        \
      for (int i = 0; i < 4; i++)                                              \
        af[i] = *(const bf16x8*)&As[BUF][hh][i * 512 + ro];                    \
      _Pragma("unroll")                                                        \
      for (int j = 0; j < 2; j++)                                              \
        bfv[j] = *(const bf16x8*)&Bs[BUF][hh][(wave * 2 + j) * 512 + ro];      \
      _Pragma("unroll")                                                        \
      for (int i = 0; i < 4; i++)                                              \
        _Pragma("unroll")                                                      \
        for (int j = 0; j < 2; j++)                                            \
          acc[i][j] = __builtin_amdgcn_mfma_f32_16x16x32_bf16(af[i], bfv[j],   \
                                                          acc[i][j], 0, 0, 0); \
    }                                                                          \
  }

  // prologue: stage tile 0 into buffer 0
  STAGE(0, 0)

  for (int it = 0; it < niter; it += 2) {
    __syncthreads();
    STAGE(1, (it + 1) * KB)
    GEMM_COMPUTE(0)
    __syncthreads();
    if (it + 2 < niter) STAGE(0, (it + 2) * KB)
    GEMM_COMPUTE(1)
  }
#undef STAGE
#undef GEMM_COMPUTE

  // epilogue: C/D layout col=lane&15, row=(lane>>4)*4+reg (verified mapping)
  const bool withBias = (gridDim.z == 1);
  OutT* Cz = C + (size_t)blockIdx.z * ((size_t)M * N);
#pragma unroll
  for (int j = 0; j < 2; j++) {
    int col = n0 + wave * 32 + j * 16 + (lane & 15);
    if (col < N) {
      float bv = withBias ? bias[col] : 0.f;
#pragma unroll
      for (int i = 0; i < 4; i++) {
        int rbase = m0 + i * 16 + (lane >> 4) * 4;
#pragma unroll
        for (int r = 0; r < 4; r++) {
          float v = acc[i][j][r] + bv;
          if constexpr (sizeof(OutT) == 2)
            Cz[(size_t)(rbase + r) * N + col] = (OutT)f2bf(v);
          else
            Cz[(size_t)(rbase + r) * N + col] = (OutT)v;
        }
      }
    }
  }
}

// ---------------- split-K reduce: out = p0 + p1 + bias ----------------
__global__ void k_reduce_out(const float* __restrict__ part, const float* __restrict__ bias,
                             float* __restrict__ out) {
  int i = blockIdx.x * 256 + threadIdx.x;   // float4 index over 2048*1024
  float4 a = ((const float4*)part)[i];
  float4 b = ((const float4*)(part + (size_t)L_SEQ * DMODEL))[i];
  int col = (i * 4) & (DMODEL - 1);
  float4 bb = *(const float4*)&bias[col];
  float4 o;
  o.x = a.x + b.x + bb.x; o.y = a.y + b.y + bb.y;
  o.z = a.z + b.z + bb.z; o.w = a.w + b.w + bb.w;
  ((float4*)out)[i] = o;
}

// ---------------- depthwise causal conv (K=4) + bias + SiLU ----------------
__global__ void k_conv_silu(const unsigned short* __restrict__ xr,
                            const float* __restrict__ Wc,
                            const float* __restrict__ bc,
                            unsigned short* __restrict__ xcb) {
  int idx = blockIdx.x * blockDim.x + threadIdx.x;
  if (idx >= L_SEQ * DI_DIM) return;
  int t = idx >> 11;
  int d = idx & (DI_DIM - 1);
  float acc = bc[d];
  const float* wd = Wc + d * 4;
  if (t >= 3) acc += bf2f(xr[(size_t)(t - 3) * (2 * DI_DIM) + d]) * wd[0];
  if (t >= 2) acc += bf2f(xr[(size_t)(t - 2) * (2 * DI_DIM) + d]) * wd[1];
  if (t >= 1) acc += bf2f(xr[(size_t)(t - 1) * (2 * DI_DIM) + d]) * wd[2];
  acc += bf2f(xr[(size_t)t * (2 * DI_DIM) + d]) * wd[3];
  xcb[idx] = f2bf(siluf(acc));
}

// ---------------- scan phase A: per-chunk local scan ----------------
__global__ __launch_bounds__(256) void k_scan_a(
    const float* __restrict__ proj, const unsigned short* __restrict__ xcb,
    const float* __restrict__ A_log,
    float* __restrict__ Sdelta, float* __restrict__ hstate) {
  __shared__ float Bsh[LCHUNK * NSSM];
  const int d = blockIdx.x * 256 + threadIdx.x;
  const int c = blockIdx.y;
  const int t0 = c * LCHUNK;
  for (int i = threadIdx.x; i < LCHUNK * NSSM; i += 256) {
    int t = i >> 4, n = i & 15;
    Bsh[i] = proj[(size_t)(t0 + t) * NPROJ + DI_DIM + n];
  }
  __syncthreads();
  float Ar[NSSM], h[NSSM];
#pragma unroll
  for (int n = 0; n < NSSM; n++) {
    Ar[n] = -__expf(A_log[d * NSSM + n]);
    h[n] = 0.f;
  }
  const float* pp = proj + (size_t)t0 * NPROJ + d;
  const unsigned short* xp = xcb + (size_t)t0 * DI_DIM + d;
  float p_nxt = pp[0];
  unsigned short x_nxt = xp[0];
  float sd = 0.f;
  for (int t = 0; t < LCHUNK; t++) {
    float p = p_nxt;
    unsigned short xu = x_nxt;
    if (t + 1 < LCHUNK) {                          // prefetch next step
      p_nxt = pp[(size_t)(t + 1) * NPROJ];
      x_nxt = xp[(size_t)(t + 1) * DI_DIM];
    }
    float delta = softplusf(p);
    float dx = delta * bf2f(xu);
    sd += delta;
#pragma unroll
    for (int n = 0; n < NSSM; n++)
      h[n] = __expf(delta * Ar[n]) * h[n] + dx * Bsh[t * NSSM + n];
  }
  Sdelta[(size_t)c * DI_DIM + d] = sd;
#pragma unroll
  for (int n = 0; n < NSSM; n++)
    hstate[((size_t)c * DI_DIM + d) * NSSM + n] = h[n];
}

// ---------------- scan phase B: combine across chunks (in-place) ----------------
__global__ void k_scan_b(const float* __restrict__ A_log,
                         const float* __restrict__ Sdelta,
                         float* __restrict__ hstate) {
  int tid = blockIdx.x * 256 + threadIdx.x;  // d*16+n
  int d = tid >> 4;
  float A = -__expf(A_log[tid]);
  float carry = 0.f;
  float v_nxt = hstate[tid];
  float s_nxt = Sdelta[d];
  for (int c = 0; c < NCHUNK; c++) {
    float v = v_nxt, s = s_nxt;
    if (c + 1 < NCHUNK) {                          // prefetch next chunk
      v_nxt = hstate[(size_t)(c + 1) * DI_DIM * NSSM + tid];
      s_nxt = Sdelta[(size_t)(c + 1) * DI_DIM + d];
    }
    hstate[(size_t)c * DI_DIM * NSSM + tid] = carry;
    carry = __expf(A * s) * carry + v;
  }
}

// ---------------- scan phase C: replay with h0, produce y*silu(res) ----------------
__global__ __launch_bounds__(256) void k_scan_c(
    const float* __restrict__ proj, const unsigned short* __restrict__ xcb,
    const float* __restrict__ A_log, const float* __restrict__ h0,
    const float* __restrict__ Dvec, const unsigned short* __restrict__ xr,
    unsigned short* __restrict__ ybf) {
  __shared__ float Bsh[LCHUNK * NSSM];
  __shared__ float Csh[LCHUNK * NSSM];
  const int d = blockIdx.x * 256 + threadIdx.x;
  const int c = blockIdx.y;
  const int t0 = c * LCHUNK;
  for (int i = threadIdx.x; i < LCHUNK * NSSM; i += 256) {
    int t = i >> 4, n = i & 15;
    Bsh[i] = proj[(size_t)(t0 + t) * NPROJ + DI_DIM + n];
    Csh[i] = proj[(size_t)(t0 + t) * NPROJ + DI_DIM + NSSM + n];
  }
  __syncthreads();
  float Ar[NSSM], h[NSSM];
#pragma unroll
  for (int n = 0; n < NSSM; n++) {
    Ar[n] = -__expf(A_log[d * NSSM + n]);
    h[n] = h0[((size_t)c * DI_DIM + d) * NSSM + n];
  }
  float Dd = Dvec[d];
  const float* pp = proj + (size_t)t0 * NPROJ + d;
  const unsigned short* xp = xcb + (size_t)t0 * DI_DIM + d;
  const unsigned short* rp = xr + (size_t)t0 * (2 * DI_DIM) + DI_DIM + d;
  float p_nxt = pp[0];
  unsigned short x_nxt = xp[0];
  unsigned short r_nxt = rp[0];
  for (int t = 0; t < LCHUNK; t++) {
    float p = p_nxt;
    unsigned short xu = x_nxt, ru = r_nxt;
    if (t + 1 < LCHUNK) {                          // prefetch next step
      p_nxt = pp[(size_t)(t + 1) * NPROJ];
      x_nxt = xp[(size_t)(t + 1) * DI_DIM];
      r_nxt = rp[(size_t)(t + 1) * (2 * DI_DIM)];
    }
    float delta = softplusf(p);
    float xi = bf2f(xu);
    float dx = delta * xi;
    float y = 0.f;
#pragma unroll
    for (int n = 0; n < NSSM; n++) {
      h[n] = __expf(delta * Ar[n]) * h[n] + dx * Bsh[t * NSSM + n];
      y += h[n] * Csh[t * NSSM + n];
    }
    y += xi * Dd;
    y *= siluf(bf2f(ru));
    ybf[(size_t)(t0 + t) * DI_DIM + d] = f2bf(y);
  }
}

extern "C" void kernel_launch(void* const* d_in, const int* in_sizes, int n_in,
                              void* d_out, int out_size, void* d_ws, size_t ws_size,
                              hipStream_t stream) {
  const float* x      = (const float*)d_in[0];
  const float* W_in   = (const float*)d_in[1];
  const float* b_in   = (const float*)d_in[2];
  const float* W_conv = (const float*)d_in[3];
  const float* b_conv = (const float*)d_in[4];
  const float* W_x    = (const float*)d_in[5];
  const float* b_x    = (const float*)d_in[6];
  const float* W_out  = (const float*)d_in[7];
  const float* b_out  = (const float*)d_in[8];
  const float* A_log  = (const float*)d_in[9];
  const float* Dv     = (const float*)d_in[10];
  float* out = (float*)d_out;

  char* ws = (char*)d_ws;
  size_t off = 0;
  auto alloc = [&](size_t bytes) { void* p = ws + off; off += (bytes + 255) & ~(size_t)255; return p; };
  unsigned short* win_bf = (unsigned short*)alloc((size_t)4096 * DMODEL * 2);        // 8.39 MB; reused as ybf
  unsigned short* wx_bf  = (unsigned short*)alloc((size_t)NPROJ * DI_DIM * 2);       // 8.52 MB
  unsigned short* x_bf   = (unsigned short*)alloc((size_t)L_SEQ * DMODEL * 2);       // 4.19 MB; reused as wout_bf
  unsigned short* xr_bf  = (unsigned short*)alloc((size_t)L_SEQ * 2 * DI_DIM * 2);   // 16.78 MB
  unsigned short* xcb    = (unsigned short*)alloc((size_t)L_SEQ * DI_DIM * 2);       // 8.39 MB
  float* proj            = (float*)alloc((size_t)L_SEQ * NPROJ * 4);                 // 17.04 MB; reused as GEMM3 partials
  float* Sdelta          = (float*)alloc((size_t)NCHUNK * DI_DIM * 4);               // 0.52 MB
  float* hstate          = (float*)alloc((size_t)NCHUNK * DI_DIM * NSSM * 4);        // 8.39 MB
  if (off > ws_size) return;  // proven budget: 72.2 MB
  unsigned short* ybf     = win_bf;  // dead after GEMM1, reborn as y (scan_c -> GEMM3)
  unsigned short* wout_bf = x_bf;    // dead after GEMM1, reborn as W_out bf16
  float* part             = proj;    // dead after scan_c, reborn as GEMM3 split-K partials (2 x 8.39 MB)

  // fused converts: x, W_in, W_x
  k_convert3<<<CVT_N3 / 256, 256, 0, stream>>>(x, W_in, W_x, x_bf, win_bf, wx_bf);

  // GEMM1: xr = x @ W_in^T + b_in (2048x4096, K=1024), bf16 out, KB=32, 1024 blocks (24KB LDS, 4+/CU)
  {
    dim3 g(4096 / 128, L_SEQ / 64);
    k_gemm_bt<unsigned short, 32><<<g, 256, 0, stream>>>(x_bf, win_bf, b_in, xr_bf, L_SEQ, 4096, DMODEL);
  }
  // convert W_out into x_bf's slot (x dead after GEMM1)
  k_f32_to_bf16<<<(DMODEL * DI_DIM / 4) / 256, 256, 0, stream>>>(W_out, wout_bf, DMODEL * DI_DIM / 4);
  // depthwise conv + SiLU
  k_conv_silu<<<(L_SEQ * DI_DIM) / 256, 256, 0, stream>>>(xr_bf, W_conv, b_conv, xcb);
  // GEMM2: proj = xi @ W_x^T + b_x (2048x2080, K=2048), f32 out, KB=64, 544 blocks (48KB LDS, 3/CU >= 2.1 dispatch)
  {
    dim3 g((NPROJ + 127) / 128, L_SEQ / 64);
    k_gemm_bt<float, 64><<<g, 256, 0, stream>>>(xcb, wx_bf, b_x, proj, L_SEQ, NPROJ, DI_DIM);
  }
  // selective scan (chunked 3-phase)
  {
    dim3 ga(DI_DIM / 256, NCHUNK);
    k_scan_a<<<ga, 256, 0, stream>>>(proj, xcb, A_log, Sdelta, hstate);
    k_scan_b<<<(DI_DIM * NSSM) / 256, 256, 0, stream>>>(A_log, Sdelta, hstate);
    k_scan_c<<<ga, 256, 0, stream>>>(proj, xcb, A_log, hstate, Dv, xr_bf, ybf);
  }
  // GEMM3: KB=64, split-K=2 partials (512 blocks), then reduce+bias
  {
    dim3 g(DMODEL / 128, L_SEQ / 64, 2);
    k_gemm_bt<float, 64><<<g, 256, 0, stream>>>(ybf, wout_bf, b_out, part, L_SEQ, DMODEL, DI_DIM);
    k_reduce_out<<<(L_SEQ * DMODEL / 4) / 256, 256, 0, stream>>>(part, b_out, out);
  }
}